// Round 1
// 232.992 us; speedup vs baseline: 1.0584x; 1.0584x over previous
//
#include <hip/hip_runtime.h>

// B=32, C=512, c2=256, M=1024. All GEMMs bf16 MFMA (fp32 accum), m97-style:
// 128x128 (or fused) tiles, BK=64, global_load_lds(16B) staging, XOR-swizzled
// chunks.
//
// P0 : x[b][c][sp] fp32 -> xT[b*1024+sp][c] bf16
// W0 : weight casts (Wkv = [Wk;Wv] 512x512, Wo 512x256)
// K1 : [32768x512]x[512x512]: k-half -> kT[m][c] + row-sum partials,
//      v-half -> vT[b][c][n] (reshape-permuted)
// K1b: combine 4 row-sum partials -> s_buf
// K2 : FUSED flash-style attention per (64-row m-stripe, batch), v2:
//      wave-self-contained staging in 4KB rounds, per-wave double buffer,
//      counted s_waitcnt vmcnt(4) (loads in flight across barriers), only
//      2 raw s_barriers per chunk (P-panel handoff), setprio around MFMA,
//      bijective XCD swizzle (4 batches per XCD -> L2-resident kT/vT).
// K3 : out = Wo @ O2 + bo + x (fp32), B = OB (k-major)

typedef short bf8 __attribute__((ext_vector_type(8)));
typedef float f32x4 __attribute__((ext_vector_type(4)));

#define MFMA16(a, b, c) __builtin_amdgcn_mfma_f32_16x16x32_bf16((a), (b), (c), 0, 0, 0)

__device__ __forceinline__ short f2bf(float x) {
  unsigned u = __float_as_uint(x);
  u += 0x7fffu + ((u >> 16) & 1u);   // RNE, finite inputs
  return (short)(u >> 16);
}

__device__ __forceinline__ void gll16(const short* g, void* l) {
  __builtin_amdgcn_global_load_lds(
      (const __attribute__((address_space(1))) unsigned int*)g,
      (__attribute__((address_space(3))) unsigned int*)l, 16, 0, 0);
}

__device__ __forceinline__ void lgkm0() {
  asm volatile("s_waitcnt lgkmcnt(0)" ::: "memory");
}
template <int N>
__device__ __forceinline__ void waitv() {
  static_assert(N == 0 || N == 4 || N == 8, "bad vmcnt");
  if constexpr (N == 0) asm volatile("s_waitcnt vmcnt(0)" ::: "memory");
  else if constexpr (N == 4) asm volatile("s_waitcnt vmcnt(4)" ::: "memory");
  else asm volatile("s_waitcnt vmcnt(8)" ::: "memory");
}
__device__ __forceinline__ void barrier_relaxed() {
  asm volatile("" ::: "memory");
  __builtin_amdgcn_s_barrier();
  asm volatile("" ::: "memory");
}

// ---- shared GEMM core: C[128][128] tile, A/B k-major bf16, K = ksteps*64 ----
__device__ __forceinline__ void gemm_core(const short* __restrict__ A,
                                          const short* __restrict__ B,
                                          int ldA, int ldB, int ksteps,
                                          char* smem, f32x4 acc[4][4]) {
  const int tid = threadIdx.x;
  const int w = tid >> 6, l = tid & 63;
  const int q = l >> 4, i = l & 15;
  const int wm = w & 1, wn = w >> 1;
  const int srow = l >> 3;
  const int gcol = ((l & 7) ^ srow) * 8;        // swizzled 16B chunk (shorts)
  f32x4 zz = {0.f, 0.f, 0.f, 0.f};
  #pragma unroll
  for (int mt = 0; mt < 4; ++mt)
    #pragma unroll
    for (int nt = 0; nt < 4; ++nt) acc[mt][nt] = zz;

  for (int ks = 0; ks < ksteps; ++ks) {
    __syncthreads();                            // LDS free (prev reads done)
    const short* Ak = A + ks * 64 + gcol;
    const short* Bk = B + ks * 64 + gcol;
    #pragma unroll
    for (int j = 0; j < 4; ++j) {
      int s = w * 4 + j;
      size_t row = (size_t)(s * 8 + srow);
      gll16(Ak + row * ldA, smem + s * 1024);
      gll16(Bk + row * ldB, smem + 16384 + s * 1024);
    }
    __syncthreads();                            // staged data visible
    #pragma unroll
    for (int kq = 0; kq < 2; ++kq) {
      int sw = ((kq * 4 + q) ^ (i & 7)) * 16;   // swizzled read offset (bytes)
      bf8 af[4], bq[4];
      #pragma unroll
      for (int mt = 0; mt < 4; ++mt)
        af[mt] = *(const bf8*)(smem + (wm * 64 + mt * 16 + i) * 128 + sw);
      #pragma unroll
      for (int nt = 0; nt < 4; ++nt)
        bq[nt] = *(const bf8*)(smem + 16384 + (wn * 64 + nt * 16 + i) * 128 + sw);
      #pragma unroll
      for (int mt = 0; mt < 4; ++mt)
        #pragma unroll
        for (int nt = 0; nt < 4; ++nt)
          acc[mt][nt] = MFMA16(af[mt], bq[nt], acc[mt][nt]);
    }
  }
}

// ---------------- P0: transpose + convert x ----------------
__global__ __launch_bounds__(256) void p0_xpose(const float* __restrict__ x,
                                                short* __restrict__ xT) {
  __shared__ float lds[64][65];
  int cb = blockIdx.x, sb = blockIdx.y, b = blockIdx.z;
  int t = threadIdx.x;
  int c0 = cb * 64, sp0 = sb * 64;
  const float4* x4 = reinterpret_cast<const float4*>(x);
  #pragma unroll
  for (int j = 0; j < 4; ++j) {
    int lin = t + 256 * j;
    int cl = lin >> 4, s4 = lin & 15;
    float4 v = x4[(((size_t)b * 512 + c0 + cl) * 1024 + sp0 + s4 * 4) >> 2];
    lds[cl][s4 * 4 + 0] = v.x; lds[cl][s4 * 4 + 1] = v.y;
    lds[cl][s4 * 4 + 2] = v.z; lds[cl][s4 * 4 + 3] = v.w;
  }
  __syncthreads();
  int spl = t >> 2, cs = (t & 3) * 16;
  bf8 o0, o1;
  #pragma unroll
  for (int j = 0; j < 8; ++j) o0[j] = f2bf(lds[cs + j][spl]);
  #pragma unroll
  for (int j = 0; j < 8; ++j) o1[j] = f2bf(lds[cs + 8 + j][spl]);
  size_t base = ((size_t)b * 1024 + sp0 + spl) * 512 + c0 + cs;
  *reinterpret_cast<bf8*>(xT + base) = o0;
  *reinterpret_cast<bf8*>(xT + base + 8) = o1;
}

// ---------------- W0: weight casts ----------------
__global__ __launch_bounds__(256) void w0_weights(const float* __restrict__ Wk,
                                                  const float* __restrict__ Wv,
                                                  const float* __restrict__ Wo,
                                                  short* __restrict__ Wkv_bf,
                                                  short* __restrict__ Wo_bf) {
  int g = blockIdx.x * 256 + threadIdx.x;
  if (g < 262144) {
    int o = g >> 9, c = g & 511;
    float v = (o < 256) ? Wk[o * 512 + c] : Wv[(o - 256) * 512 + c];
    Wkv_bf[g] = f2bf(v);
  } else {
    int i2 = g - 262144;
    Wo_bf[i2] = f2bf(Wo[i2]);
  }
}

// ---------------- K1: fused k/v projection GEMM ----------------
__global__ __launch_bounds__(256, 2) void k1_kv(const short* __restrict__ xT,
                                                const short* __restrict__ Wkv,
                                                const float* __restrict__ bk,
                                                const float* __restrict__ bv,
                                                short* __restrict__ kT,
                                                short* __restrict__ vT,
                                                float* __restrict__ s_part) {
  __shared__ __attribute__((aligned(16))) char smem[32768];
  f32x4 acc[4][4];
  int bm = blockIdx.x, bn = blockIdx.y;
  gemm_core(xT + (size_t)bm * 128 * 512, Wkv + (size_t)bn * 128 * 512,
            512, 512, 8, smem, acc);
  int tid = threadIdx.x;
  int w = tid >> 6, l = tid & 63, q = l >> 4, i = l & 15;
  int wm = w & 1, wn = w >> 1;
  int mbase = bm * 128 + wm * 64;
  int nbase = bn * 128 + wn * 64;
  if (bn < 2) {                                  // k half
    float rp[4][4];
    #pragma unroll
    for (int mt = 0; mt < 4; ++mt)
      #pragma unroll
      for (int r = 0; r < 4; ++r) rp[mt][r] = 0.f;
    #pragma unroll
    for (int mt = 0; mt < 4; ++mt)
      #pragma unroll
      for (int nt = 0; nt < 4; ++nt) {
        float bias = bk[nbase + nt * 16 + i];
        #pragma unroll
        for (int r = 0; r < 4; ++r) {
          float val = acc[mt][nt][r] + bias;
          int mg = mbase + mt * 16 + q * 4 + r;
          kT[(size_t)mg * 256 + nbase + nt * 16 + i] = f2bf(val);
          rp[mt][r] += val;
        }
      }
    #pragma unroll
    for (int mask = 1; mask <= 8; mask <<= 1)
      #pragma unroll
      for (int mt = 0; mt < 4; ++mt)
        #pragma unroll
        for (int r = 0; r < 4; ++r) rp[mt][r] += __shfl_xor(rp[mt][r], mask, 64);
    if (i == 0) {
      int pg = bn * 2 + wn;
      #pragma unroll
      for (int mt = 0; mt < 4; ++mt)
        #pragma unroll
        for (int r = 0; r < 4; ++r)
          s_part[pg * 32768 + mbase + mt * 16 + q * 4 + r] = rp[mt][r];
    }
  } else {                                       // v half -> vT permuted
    #pragma unroll
    for (int mt = 0; mt < 4; ++mt)
      #pragma unroll
      for (int nt = 0; nt < 4; ++nt) {
        int o2 = nbase + nt * 16 + i - 256;
        float bias = bv[o2];
        #pragma unroll
        for (int r = 0; r < 4; ++r) {
          float val = acc[mt][nt][r] + bias;
          int mg = mbase + mt * 16 + q * 4 + r;
          int b = mg >> 10, sp = mg & 1023;
          vT[((size_t)b * 256 + (sp & 255)) * 1024 + 4 * o2 + (sp >> 8)] = f2bf(val);
        }
      }
  }
}

__global__ __launch_bounds__(256) void k1b_sum(const float* __restrict__ s_part,
                                               float* __restrict__ s_buf) {
  int t = blockIdx.x * 256 + threadIdx.x;
  s_buf[t] = s_part[t] + s_part[32768 + t] + s_part[65536 + t] + s_part[98304 + t];
}

// ---------------- K2 v2: fused gram -> softmax -> PV -> OB ----------------
// Block = (64-row m-stripe bm, batch b), XCD-swizzled so each XCD owns 4
// batches. LDS: Apan 32K resident | Ppan 16K | Bst 32K = 2 bufs x 4 waves x
// 4KB. All staging wave-self-contained: counted vmcnt(4) instead of
// barrier+drain; exactly 2 rounds (8 gll16) in flight at every wait; only 2
// raw s_barriers per chunk (P-panel handoff). 2 blocks/CU.
__global__ __launch_bounds__(256, 2) void k2_fused(const short* __restrict__ kT,
                                                   const short* __restrict__ vT,
                                                   const float* __restrict__ s_buf,
                                                   short* __restrict__ OB) {
  __shared__ __attribute__((aligned(16))) char smem[81920];
  char* Apan = smem;            // 32 KB: 4 k-panels x (64 rows x 128 B)
  char* Ppan = smem + 32768;    // 16 KB: 2 panels x (64 rows x 128 B)
  char* Bst  = smem + 49152;    // 32 KB: 2 bufs x 4 waves x 4 KB

  const int id = blockIdx.x;
  const int xcd = id & 7, slot = id >> 3;
  const int b  = xcd * 4 + (slot >> 4);   // 4 batches per XCD (L2-resident)
  const int bm = slot & 15;

  const int tid = threadIdx.x;
  const int w = tid >> 6, l = tid & 63;
  const int q = l >> 4, i = l & 15;
  const int srow = l >> 3;
  const int gcol = ((l & 7) ^ srow) * 8;

  const short* kTb = kT + (size_t)b * 1024 * 256;
  const short* vTb = vT + (size_t)b * 256 * 1024;
  const float* sB = s_buf + b * 1024;

  char* slabA = Bst + w * 4096;            // even rounds
  char* slabB = Bst + 16384 + w * 4096;    // odd rounds

  const float sc1 = 1.0f / 16384.0f;             // (1/M)/16
  const float sc2 = 1.0f / 16777216.0f;          // (1/M^2)/16

  // ---- prefetch ALL scalar loads (steady-state loop issues only gll16) ----
  float sm2[4][4];
  #pragma unroll
  for (int mt = 0; mt < 4; ++mt)
    #pragma unroll
    for (int r = 0; r < 4; ++r)
      sm2[mt][r] = sB[bm * 64 + mt * 16 + q * 4 + r] * sc2;
  float sn[8][2];
  #pragma unroll
  for (int c = 0; c < 8; ++c) {
    sn[c][0] = sB[c * 128 + w * 32 + i];
    sn[c][1] = sB[c * 128 + w * 32 + 16 + i];
  }

  // staging helpers: each wave stages exactly the rows its MFMAs read
  auto stageS = [&](int c, int ks, char* sl) {
    const short* Bn = kTb + (size_t)c * 128 * 256 + ks * 64 + gcol;
    #pragma unroll
    for (int j = 0; j < 4; ++j)
      gll16(Bn + (size_t)(w * 32 + j * 8 + srow) * 256, sl + j * 1024);
  };
  auto stageV = [&](int c, int ks2, int h, char* sl) {
    const short* Vn = vTb + c * 128 + ks2 * 64 + gcol;
    #pragma unroll
    for (int j = 0; j < 4; ++j)
      gll16(Vn + (size_t)(w * 64 + h * 32 + j * 8 + srow) * 1024, sl + j * 1024);
  };

  // ---- stage resident A stripe (cross-wave) + first two S rounds ----
  {
    const short* Am = kTb + (size_t)bm * 64 * 256;
    #pragma unroll
    for (int ks = 0; ks < 4; ++ks)
      #pragma unroll
      for (int j2 = 0; j2 < 2; ++j2) {
        int s2 = w * 2 + j2;
        gll16(Am + (size_t)(s2 * 8 + srow) * 256 + ks * 64 + gcol,
              Apan + ks * 8192 + s2 * 1024);
      }
  }
  stageS(0, 0, slabA);                     // round 0
  stageS(0, 1, slabB);                     // round 1
  waitv<8>();                              // A landed; rounds 0/1 in flight
  barrier_relaxed();                       // A visible to all waves

  f32x4 zz = {0.f, 0.f, 0.f, 0.f};
  f32x4 acc_o[4][4];
  float rowsum[4][4];
  #pragma unroll
  for (int mt = 0; mt < 4; ++mt)
    #pragma unroll
    for (int ct = 0; ct < 4; ++ct) acc_o[mt][ct] = zz;
  #pragma unroll
  for (int mt = 0; mt < 4; ++mt)
    #pragma unroll
    for (int r = 0; r < 4; ++r) rowsum[mt][r] = 0.f;

  #pragma unroll
  for (int c = 0; c < 8; ++c) {
    f32x4 acc_s[4][2];
    #pragma unroll
    for (int mt = 0; mt < 4; ++mt)
      #pragma unroll
      for (int nt = 0; nt < 2; ++nt) acc_s[mt][nt] = zz;

    // ---- S rounds ks=0..3 (K=256): wait own vmcnt, compute, refill slab ----
    #pragma unroll
    for (int ks = 0; ks < 4; ++ks) {
      char* sl = (ks & 1) ? slabB : slabA;
      waitv<4>();                          // this round done; next in flight
      #pragma unroll
      for (int kq = 0; kq < 2; ++kq) {
        int sw = ((kq * 4 + q) ^ (i & 7)) * 16;
        bf8 af[4], bq2[2];
        #pragma unroll
        for (int mt = 0; mt < 4; ++mt)
          af[mt] = *(const bf8*)(Apan + ks * 8192 + (mt * 16 + i) * 128 + sw);
        #pragma unroll
        for (int nt = 0; nt < 2; ++nt)
          bq2[nt] = *(const bf8*)(sl + (nt * 16 + i) * 128 + sw);
        __builtin_amdgcn_s_setprio(1);
        #pragma unroll
        for (int mt = 0; mt < 4; ++mt)
          #pragma unroll
          for (int nt = 0; nt < 2; ++nt)
            acc_s[mt][nt] = MFMA16(af[mt], bq2[nt], acc_s[mt][nt]);
        __builtin_amdgcn_s_setprio(0);
      }
      lgkm0();                             // slab reads retired before refill
      if (ks < 2) stageS(c, ks + 2, sl);   // rounds 2,3: S ks+2
      else        stageV(c, 0, ks - 2, sl);// rounds 4,5: PV ks2=0, halves 0,1
    }

    // ---- exp -> P panels (PV rounds 4,5 in flight under this VALU work) ----
    barrier_relaxed();                     // prev chunk's P readers all done
    #pragma unroll
    for (int nt = 0; nt < 2; ++nt) {
      float snv = sn[c][nt];
      int nl = w * 32 + nt * 16 + i;
      char* pbase = Ppan + (nl >> 6) * 8192 + (nl & 7) * 2;
      int gchunk = (nl >> 3) & 7;
      #pragma unroll
      for (int mt = 0; mt < 4; ++mt)
        #pragma unroll
        for (int r = 0; r < 4; ++r) {
          int ml = mt * 16 + q * 4 + r;
          float p = __expf(acc_s[mt][nt][r] * sc1 - sm2[mt][r] * snv);
          rowsum[mt][r] += p;
          *(short*)(pbase + ml * 128 + ((gchunk ^ (ml & 7)) * 16)) = f2bf(p);
        }
    }
    lgkm0();                               // P writes complete
    barrier_relaxed();                     // P visible to all waves

    // ---- PV rounds (ks2,h) = (0,0),(0,1),(1,0),(1,1), K=128 ----
    #pragma unroll
    for (int pv = 0; pv < 4; ++pv) {
      char* sl = (pv & 1) ? slabB : slabA;
      const int ks2 = pv >> 1, h = pv & 1;
      if (c == 7 && pv == 3) waitv<0>(); else waitv<4>();
      #pragma unroll
      for (int kq = 0; kq < 2; ++kq) {
        int sw = ((kq * 4 + q) ^ (i & 7)) * 16;
        bf8 ap[4], bv2[2];
        #pragma unroll
        for (int mt = 0; mt < 4; ++mt)
          ap[mt] = *(const bf8*)(Ppan + ks2 * 8192 + (mt * 16 + i) * 128 + sw);
        #pragma unroll
        for (int u = 0; u < 2; ++u)
          bv2[u] = *(const bf8*)(sl + (u * 16 + i) * 128 + sw);
        __builtin_amdgcn_s_setprio(1);
        #pragma unroll
        for (int mt = 0; mt < 4; ++mt)
          #pragma unroll
          for (int u = 0; u < 2; ++u)
            acc_o[mt][h * 2 + u] = MFMA16(ap[mt], bv2[u], acc_o[mt][h * 2 + u]);
        __builtin_amdgcn_s_setprio(0);
      }
      lgkm0();
      if (pv < 2) stageV(c, 1, pv, sl);            // rounds 6,7: PV ks2=1
      else if (c < 7) stageS(c + 1, pv - 2, sl);   // next chunk S0,S1
    }
  }

  // ---- softmax rowsums: wave-reduce over i, block-reduce over waves ----
  #pragma unroll
  for (int mask = 1; mask <= 8; mask <<= 1)
    #pragma unroll
    for (int mt = 0; mt < 4; ++mt)
      #pragma unroll
      for (int r = 0; r < 4; ++r) rowsum[mt][r] += __shfl_xor(rowsum[mt][r], mask, 64);
  __syncthreads();                               // all PV P-reads done; reuse Ppan
  float* rs = (float*)Ppan;                      // [4 waves][64 m]
  if (i == 0) {
    #pragma unroll
    for (int mt = 0; mt < 4; ++mt)
      #pragma unroll
      for (int r = 0; r < 4; ++r)
        rs[w * 64 + mt * 16 + q * 4 + r] = rowsum[mt][r];
  }
  __syncthreads();
  float rinv[4][4];
  #pragma unroll
  for (int mt = 0; mt < 4; ++mt)
    #pragma unroll
    for (int r = 0; r < 4; ++r) {
      int m = mt * 16 + q * 4 + r;
      rinv[mt][r] = 1.0f / (rs[m] + rs[64 + m] + rs[128 + m] + rs[192 + m]);
    }
  // ---- normalize + OB write via per-wave LDS restage (self-contained slot) ----
  short* ob = (short*)(Bst + w * 8192);          // 256 rows x 16 shorts
  #pragma unroll
  for (int mt = 0; mt < 4; ++mt)
    #pragma unroll
    for (int ct = 0; ct < 4; ++ct)
      #pragma unroll
      for (int r = 0; r < 4; ++r)
        ob[(r * 64 + ct * 16 + i) * 16 + mt * 4 + q] =
            f2bf(acc_o[mt][ct][r] * rinv[mt][r]);
  short* obg = OB + (size_t)b * 1024 * 256;
  #pragma unroll
  for (int jj = 0; jj < 8; ++jj) {
    int lr = jj * 32 + (l >> 1), ch = l & 1;
    bf8 vv = *(const bf8*)(ob + lr * 16 + ch * 8);
    int rr = lr >> 6, cc = lr & 63;
    *(bf8*)(obg + ((size_t)(rr * 256 + w * 64 + cc)) * 256 + bm * 16 + ch * 8) = vv;
  }
}

// ---------------- K3: output projection + bias + residual ----------------
__global__ __launch_bounds__(256, 2) void k3_out(const short* __restrict__ Wo_bf,
                                                 const short* __restrict__ OB,
                                                 const float* __restrict__ bo,
                                                 const float* __restrict__ x,
                                                 float* __restrict__ out) {
  __shared__ __attribute__((aligned(16))) char smem[32768];
  f32x4 acc[4][4];
  int bm = blockIdx.x, bn = blockIdx.y, b = blockIdx.z;
  gemm_core(Wo_bf + (size_t)bm * 128 * 256,
            OB + ((size_t)b * 1024 + bn * 128) * 256, 256, 256, 4, smem, acc);
  int tid = threadIdx.x;
  int w = tid >> 6, l = tid & 63, q = l >> 4, i = l & 15;
  int wm = w & 1, wn = w >> 1;
  int oloc = bm * 128 + wm * 64, sploc = bn * 128 + wn * 64;
  #pragma unroll
  for (int mt = 0; mt < 4; ++mt)
    #pragma unroll
    for (int r = 0; r < 4; ++r) {
      int o = oloc + mt * 16 + q * 4 + r;
      float bias = bo[o];
      #pragma unroll
      for (int nt = 0; nt < 4; ++nt) {
        int sp = sploc + nt * 16 + i;
        size_t idx = ((size_t)b * 512 + o) * 1024 + sp;
        out[idx] = acc[mt][nt][r] + bias + x[idx];
      }
    }
}

extern "C" void kernel_launch(void* const* d_in, const int* in_sizes, int n_in,
                              void* d_out, int out_size, void* d_ws, size_t ws_size,
                              hipStream_t stream) {
  (void)in_sizes; (void)n_in; (void)out_size; (void)ws_size;
  const float* x  = (const float*)d_in[0];
  const float* Wk = (const float*)d_in[1];
  const float* bk = (const float*)d_in[2];
  const float* Wv = (const float*)d_in[3];
  const float* bv = (const float*)d_in[4];
  const float* Wo = (const float*)d_in[5];
  const float* bo = (const float*)d_in[6];
  float* out = (float*)d_out;
  char* ws = (char*)d_ws;

  // ws layout (~68.5 MB), time-aliased:
  //   [0,32M)   : xT (P0->K1, 32 MB) then OB (K2->K3, 16 MB)
  //   [32M,48M) : kT (K1->K2)
  //   [48M,64M) : vT (K1->K2)
  //   [64M,...) : weights + reduction buffers
  short* xT     = (short*)(ws);
  short* OB     = (short*)(ws);
  short* kTb    = (short*)(ws + 33554432);
  short* vTb    = (short*)(ws + 50331648);
  short* Wkv_bf = (short*)(ws + 67108864);
  short* Wo_bf  = (short*)(ws + 67633152);
  float* s_part = (float*)(ws + 67895296);
  float* s_buf  = (float*)(ws + 68419584);

  p0_xpose<<<dim3(8, 16, 32), 256, 0, stream>>>(x, xT);
  w0_weights<<<1536, 256, 0, stream>>>(Wk, Wv, Wo, Wkv_bf, Wo_bf);
  k1_kv<<<dim3(256, 4), 256, 0, stream>>>(xT, Wkv_bf, bk, bv, kTb, vTb, s_part);
  k1b_sum<<<128, 256, 0, stream>>>(s_part, s_buf);
  k2_fused<<<dim3(512), 256, 0, stream>>>(kTb, vTb, s_buf, OB);
  k3_out<<<dim3(4, 8, 32), 256, 0, stream>>>(Wo_bf, OB, bo, x, out);
}